// Round 17
// baseline (451.324 us; speedup 1.0000x reference)
//
#include <hip/hip_runtime.h>
#include <hip/hip_bf16.h>
#include <cstdint>
#include <cstddef>

typedef __bf16 bf16_t;
typedef __bf16 bf16x4 __attribute__((ext_vector_type(4)));
typedef __bf16 bf16x8 __attribute__((ext_vector_type(8)));
typedef float f32x4 __attribute__((ext_vector_type(4)));

#define GLD16(src, dst)                                                       \
    __builtin_amdgcn_global_load_lds(                                         \
        (const __attribute__((address_space(1))) void*)(src),                 \
        (__attribute__((address_space(3))) void*)(dst), 16, 0, 0)

// s_barrier WITH compiler memory fence (R8 lesson).
#define BAR() asm volatile("s_barrier" ::: "memory")
#define WAIT_VM4() asm volatile("s_waitcnt vmcnt(4)" ::: "memory")
#define WAIT_VM6() asm volatile("s_waitcnt vmcnt(6)" ::: "memory")
#define WAIT_VM0() asm volatile("s_waitcnt vmcnt(0)" ::: "memory")

// ---------------------------------------------------------------------------
// x fp32 -> bf16, vectorized (G13)
// ---------------------------------------------------------------------------
__global__ __launch_bounds__(256) void cvt_x_kernel(const float* __restrict__ x,
                                                    bf16_t* __restrict__ xb, int n4) {
    int idx = blockIdx.x * blockDim.x + threadIdx.x;
    int stride = gridDim.x * blockDim.x;
    const f32x4* xv = (const f32x4*)x;
    bf16x4* ov = (bf16x4*)xb;
    for (int i = idx; i < n4; i += stride) {
        f32x4 v = xv[i];
        bf16x4 o;
        o[0] = (bf16_t)v[0];
        o[1] = (bf16_t)v[1];
        o[2] = (bf16_t)v[2];
        o[3] = (bf16_t)v[3];
        ov[i] = o;
    }
}

// ---------------------------------------------------------------------------
// Build Mt[n][k] (bf16, [N][K]) from the quaternion Hamilton block structure.
// ---------------------------------------------------------------------------
__global__ __launch_bounds__(256) void pack_w_kernel(const float* __restrict__ Wa,
                                                     const float* __restrict__ Wb,
                                                     const float* __restrict__ Wc,
                                                     const float* __restrict__ Wd,
                                                     bf16_t* __restrict__ Mt) {
    __shared__ float tile[64][65];
    const int kb = blockIdx.x * 64;
    const int nb = blockIdx.y * 64;
    const int i = kb >> 10;
    const int j = nb >> 10;

    const float* W[4] = {Wa, Wb, Wc, Wd};
    const int srcIdx[4][4] = {{0, 1, 2, 3}, {1, 0, 3, 2}, {2, 3, 0, 1}, {3, 2, 1, 0}};
    const float sgn[4][4] = {{1.f, 1.f, 1.f, 1.f},
                             {-1.f, 1.f, -1.f, 1.f},
                             {-1.f, 1.f, 1.f, -1.f},
                             {-1.f, -1.f, 1.f, 1.f}};
    const float* Ws = W[srcIdx[i][j]];
    const float s = sgn[i][j];

    const int kq = kb & 1023;
    const int nq = nb & 1023;
    const int tx = threadIdx.x & 63;
    const int ty = threadIdx.x >> 6;

    for (int r = ty; r < 64; r += 4)
        tile[r][tx] = Ws[(size_t)(kq + r) * 1024 + (nq + tx)];
    __syncthreads();
    for (int r = ty; r < 64; r += 4)
        Mt[(size_t)(nb + r) * 4096 + (kb + tx)] = (bf16_t)(s * tile[tx][r]);
}

// ---------------------------------------------------------------------------
// 256x256 GEMM — FULL READ-AHEAD PIPELINE, 1 barrier/phase (4/tile).
//
// R16 post-mortem: same-interval read->consume (a_mh0-m23@p0->mmac00,
// a_mh1-m23@p2->mmac11) puts the LDS drain ON the critical path; stage-only
// barrier intervals waste 4 barriers/tile.  This round: every fragment read
// >=1 phase before its consuming MFMA; phase = [stage; future-reads; mmac]BAR.
//
// Read schedule (consumers in parens):
//   prologue: b0(0), a_mh0(0)
//   p0: stage Ah1(t+1,IDLE); read b1(t)        (mmac01@p1, mmac11@p2); mmac00
//   p1: stage Bh0(t+2);      read a_mh1(t) x8  (mmac11@p2, mmac10@p3); mmac01
//   p2: stage Bh1(t+2);      mmac11; VM4(/VM0)
//   p3: stage Ah0(t+2);      mmac10; read b0(t+1), a_mh0(t+1) x12 (p0/p1 next)
//
// Sync ledger (1 BAR/phase, re-audited):
//  RAW cross-wave: p3 reads of t+1 need all t+1 stages drained by EVERY
//   issuer + common barrier: VM4@p2 (outstanding 12 -> keeps 4 = Bh0/Bh1(t+2),
//   drains trio(t+1)+Ah1(t+1)) then BAR(p2) => safe.  b1(t)@p0: Bh1(t) staged
//   p2(t-2), drained VM4@p2(t-1)+BARs.  a_mh1(t)@p1: Ah1(t) staged p0(t-1),
//   drained VM4@p2(t-1)+BARs.
//  WAR: Bh0(t+2)@p1 vs b0(t) reads: consumed mmac00@p0, lgkm-complete before
//   BAR(p0) => stage after BAR(p0) OK.  Bh1(t+2)@p2 vs b1(t): consumed
//   mmac01@p1 < BAR(p1) OK.  Ah0(t+2)@p3 vs a-reads (both mh sets hit wave's
//   h=wr region): a_mh1 consumed mmac11@p2 < BAR(p2) OK.  Ah1(t+1)@p0 ->
//   IDLE buf; its region's reads (a_mh1(t-1)) completed before BAR(p2,t-1).
//  In-flight-across-BAR reads all target regions staged >=1 barrier after
//   their consumer's lgkm point (checked per region above).
//  Tails: VM0@p2 when tt+2>=NT; p3 preloads guarded tt+1<NT.
// Registers: a0/a1 (2 A-sets, 64 VGPR) + b0/b1 (32) + acc (128) ~= 245.
// ---------------------------------------------------------------------------
__global__ __launch_bounds__(512, 2) void qgemm_kernel(const bf16_t* __restrict__ A,
                                                       const bf16_t* __restrict__ Bt,
                                                       const float* __restrict__ bias,
                                                       float* __restrict__ C) {
    constexpr int N = 4096, K = 4096;
    constexpr int NT = K / 64;
    extern __shared__ __align__(16) char lds[];

    const int tid = threadIdx.x;
    const int w = tid >> 6;
    const int lane = tid & 63;
    const int l15 = lane & 15, l4 = lane >> 4;
    const int wr = w >> 2, wc = w & 3;  // 2 x 4 wave grid

    // XCD-aware swizzle (512 = 8*64, bijective)
    const int wg = blockIdx.x;
    const int swz = (wg & 7) * 64 + (wg >> 3);
    const int brow = (swz >> 4) * 256;  // 32 tile rows
    const int bcol = (swz & 15) * 256;  // 16 tile cols

    // staging: LDS stores k-block' = kb ^ (row&7); dest linear, global source
    // k-block for lane slot (lane&7) at row (lane>>3) is the inverse perm:
    const int srow = lane >> 3;
    const int skb = (lane & 7) ^ (lane >> 3);

    auto stageA = [&](int buf, int h, int tt) {
#pragma unroll
        for (int q = 0; q < 2; ++q) {
            const bf16_t* src = A + (size_t)(brow + h * 128 + w * 16 + q * 8 + srow) * K +
                                tt * 64 + skb * 8;
            GLD16(src, lds + buf * 32768 + h * 16384 + w * 2048 + q * 1024);
        }
    };
    auto stageB = [&](int buf, int h, int tt) {
#pragma unroll
        for (int q = 0; q < 2; ++q) {
            const bf16_t* src = Bt + (size_t)(bcol + h * 128 + w * 16 + q * 8 + srow) * K +
                                tt * 64 + skb * 8;
            GLD16(src, lds + 65536 + buf * 32768 + h * 16384 + w * 2048 + q * 1024);
        }
    };

    f32x4 acc[8][4] = {};
    bf16x8 a0[4][2], a1[4][2], b0[2][2], b1[2][2];

    // full A m-half set (8 reads) into the given register set
    auto ldAset = [&](int buf, int mh, bf16x8(&a)[4][2]) {
#pragma unroll
        for (int m = 0; m < 4; ++m)
#pragma unroll
            for (int c = 0; c < 2; ++c)
                a[m][c] = *(const bf16x8*)(lds + buf * 32768 + wr * 16384 +
                                           (mh * 64 + m * 16 + l15) * 128 +
                                           ((c * 4 + l4) ^ (l15 & 7)) * 16);
    };
    // B frags: nh selects the STAGING half; wave cols = nh*128 + wc*32 + n*16
    auto ldB = [&](int buf, int nh, bf16x8(&b)[2][2]) {
#pragma unroll
        for (int n = 0; n < 2; ++n)
#pragma unroll
            for (int c = 0; c < 2; ++c)
                b[n][c] = *(const bf16x8*)(lds + 65536 + buf * 32768 + nh * 16384 +
                                           (wc * 32 + n * 16 + l15) * 128 +
                                           ((c * 4 + l4) ^ (l15 & 7)) * 16);
    };
    // c outermost: 8 independent MFMAs between accumulator reuses.
    auto mmac = [&](bf16x8(&a)[4][2], int mh, int nh, bf16x8(&b)[2][2]) {
        __builtin_amdgcn_s_setprio(1);
#pragma unroll
        for (int c = 0; c < 2; ++c)
#pragma unroll
            for (int m = 0; m < 4; ++m)
#pragma unroll
                for (int n = 0; n < 2; ++n)
                    acc[mh * 4 + m][nh * 2 + n] = __builtin_amdgcn_mfma_f32_16x16x32_bf16(
                        a[m][c], b[n][c], acc[mh * 4 + m][nh * 2 + n], 0, 0, 0);
        __builtin_amdgcn_s_setprio(0);
    };

// One K-tile with LITERAL buffer index CUR; reads feed FUTURE phases only.
#define TILE_BODY(CUR, TT)                                                    \
    {                                                                         \
        const int tt = (TT);                                                  \
        /* p0: consume a0,b0 (read last p3); read b1(t); stage Ah1(t+1) */    \
        if (tt + 1 < NT) stageA((CUR) ^ 1, 1, tt + 1);                        \
        ldB((CUR), 1, b1);                                                    \
        mmac(a0, 0, 0, b0);                                                   \
        BAR();                                                                \
        /* p1: consume a0,b1; read a_mh1(t); stage Bh0(t+2) */                \
        if (tt + 2 < NT) stageB((CUR), 0, tt + 2);                            \
        ldAset((CUR), 1, a1);                                                 \
        mmac(a0, 0, 1, b1);                                                   \
        BAR();                                                                \
        /* p2: consume a1,b1; stage Bh1(t+2); counted drain */                \
        if (tt + 2 < NT) stageB((CUR), 1, tt + 2);                            \
        mmac(a1, 1, 1, b1);                                                   \
        if (tt + 2 < NT) {                                                    \
            WAIT_VM4();                                                       \
        } else {                                                              \
            WAIT_VM0();                                                       \
        }                                                                     \
        BAR();                                                                \
        /* p3: consume a1,b0; stage Ah0(t+2); preload b0,a_mh0 of t+1 */      \
        if (tt + 2 < NT) stageA((CUR), 0, tt + 2);                            \
        mmac(a1, 1, 0, b0);                                                   \
        if (tt + 1 < NT) {                                                    \
            ldB((CUR) ^ 1, 0, b0);                                            \
            ldAset((CUR) ^ 1, 0, a0);                                         \
        }                                                                     \
        BAR();                                                                \
    }

    // prologue: tile0 full (8 loads, buf0) + tile1's Bh0/Bh1/Ah0 (6, buf1);
    // VM6 drains tile0 (issuer drain), BAR (common), preload b0(0), a_mh0(0).
    stageA(0, 0, 0);
    stageA(0, 1, 0);
    stageB(0, 0, 0);
    stageB(0, 1, 0);
    stageB(1, 0, 1);
    stageB(1, 1, 1);
    stageA(1, 0, 1);
    WAIT_VM6();
    BAR();
    ldB(0, 0, b0);
    ldAset(0, 0, a0);

    // main loop: 2 K-tiles per iteration, buf indices compile-time 0/1
    for (int it = 0; it < NT / 2; ++it) {
        TILE_BODY(0, 2 * it);
        TILE_BODY(1, 2 * it + 1);
    }
#undef TILE_BODY

    // epilogue: C/D layout col = lane&15, row = (lane>>4)*4 + i.
    // B mapping: global n -> col = (n>>1)*128 + wc*32 + (n&1)*16
#pragma unroll
    for (int n = 0; n < 4; ++n) {
        const int col = bcol + (n >> 1) * 128 + wc * 32 + (n & 1) * 16 + l15;
        const float bv = bias[col];
#pragma unroll
        for (int m = 0; m < 8; ++m) {
            const int row0 = brow + wr * 128 + m * 16 + l4 * 4;
            const f32x4 v = acc[m][n];
#pragma unroll
            for (int i = 0; i < 4; ++i)
                C[(size_t)(row0 + i) * N + col] = v[i] + bv;
        }
    }
}

// ---------------------------------------------------------------------------
extern "C" void kernel_launch(void* const* d_in, const int* in_sizes, int n_in,
                              void* d_out, int out_size, void* d_ws, size_t ws_size,
                              hipStream_t stream) {
    const float* x = (const float*)d_in[0];
    const float* Wa = (const float*)d_in[1];
    const float* Wb = (const float*)d_in[2];
    const float* Wc = (const float*)d_in[3];
    const float* Wd = (const float*)d_in[4];
    const float* bias = (const float*)d_in[5];
    float* out = (float*)d_out;

    const int M = 8192, N = 4096, K = 4096;

    bf16_t* xb = (bf16_t*)d_ws;       // [M][K] bf16
    bf16_t* Mt = xb + (size_t)M * K;  // [N][K] bf16

    cvt_x_kernel<<<4096, 256, 0, stream>>>(x, xb, (M * K) / 4);
    pack_w_kernel<<<dim3(64, 64), 256, 0, stream>>>(Wa, Wb, Wc, Wd, Mt);

    (void)hipFuncSetAttribute((const void*)qgemm_kernel,
                              hipFuncAttributeMaxDynamicSharedMemorySize, 131072);
    qgemm_kernel<<<dim3((M / 256) * (N / 256)), 512, 131072, stream>>>(xb, Mt, bias, out);
}

// Round 18
// 281.643 us; speedup vs baseline: 1.6025x; 1.6025x over previous
//
#include <hip/hip_runtime.h>
#include <hip/hip_bf16.h>
#include <cstdint>
#include <cstddef>

typedef __bf16 bf16_t;
typedef __bf16 bf16x4 __attribute__((ext_vector_type(4)));
typedef __bf16 bf16x8 __attribute__((ext_vector_type(8)));
typedef float f32x4 __attribute__((ext_vector_type(4)));

#define GLD16(src, dst)                                                       \
    __builtin_amdgcn_global_load_lds(                                         \
        (const __attribute__((address_space(1))) void*)(src),                 \
        (__attribute__((address_space(3))) void*)(dst), 16, 0, 0)

// s_barrier WITH compiler memory fence (R8 lesson).
#define BAR() asm volatile("s_barrier" ::: "memory")
#define WAIT_VM4() asm volatile("s_waitcnt vmcnt(4)" ::: "memory")
#define WAIT_VM6() asm volatile("s_waitcnt vmcnt(6)" ::: "memory")
#define WAIT_VM0() asm volatile("s_waitcnt vmcnt(0)" ::: "memory")

// ---------------------------------------------------------------------------
// x fp32 -> bf16, vectorized (G13)
// ---------------------------------------------------------------------------
__global__ __launch_bounds__(256) void cvt_x_kernel(const float* __restrict__ x,
                                                    bf16_t* __restrict__ xb, int n4) {
    int idx = blockIdx.x * blockDim.x + threadIdx.x;
    int stride = gridDim.x * blockDim.x;
    const f32x4* xv = (const f32x4*)x;
    bf16x4* ov = (bf16x4*)xb;
    for (int i = idx; i < n4; i += stride) {
        f32x4 v = xv[i];
        bf16x4 o;
        o[0] = (bf16_t)v[0];
        o[1] = (bf16_t)v[1];
        o[2] = (bf16_t)v[2];
        o[3] = (bf16_t)v[3];
        ov[i] = o;
    }
}

// ---------------------------------------------------------------------------
// Build Mt[n][k] (bf16, [N][K]) from the quaternion Hamilton block structure.
// ---------------------------------------------------------------------------
__global__ __launch_bounds__(256) void pack_w_kernel(const float* __restrict__ Wa,
                                                     const float* __restrict__ Wb,
                                                     const float* __restrict__ Wc,
                                                     const float* __restrict__ Wd,
                                                     bf16_t* __restrict__ Mt) {
    __shared__ float tile[64][65];
    const int kb = blockIdx.x * 64;
    const int nb = blockIdx.y * 64;
    const int i = kb >> 10;
    const int j = nb >> 10;

    const float* W[4] = {Wa, Wb, Wc, Wd};
    const int srcIdx[4][4] = {{0, 1, 2, 3}, {1, 0, 3, 2}, {2, 3, 0, 1}, {3, 2, 1, 0}};
    const float sgn[4][4] = {{1.f, 1.f, 1.f, 1.f},
                             {-1.f, 1.f, -1.f, 1.f},
                             {-1.f, 1.f, 1.f, -1.f},
                             {-1.f, -1.f, 1.f, 1.f}};
    const float* Ws = W[srcIdx[i][j]];
    const float s = sgn[i][j];

    const int kq = kb & 1023;
    const int nq = nb & 1023;
    const int tx = threadIdx.x & 63;
    const int ty = threadIdx.x >> 6;

    for (int r = ty; r < 64; r += 4)
        tile[r][tx] = Ws[(size_t)(kq + r) * 1024 + (nq + tx)];
    __syncthreads();
    for (int r = ty; r < 64; r += 4)
        Mt[(size_t)(nb + r) * 4096 + (kb + tx)] = (bf16_t)(s * tile[tx][r]);
}

// ---------------------------------------------------------------------------
// 256x256 GEMM — R16 (unrolled x2, proven) + decoupled reads, ZERO new regs.
//
// R17 post-mortem: dual A-sets -> ~250 VGPR -> spill (FETCH/WRITE ballooned,
// MfmaUtil 26%).  This round keeps R16's exact register set and schedule,
// moving only 4 ds_reads so NO mmac consumes a fragment read in its own
// barrier interval (WAR-on-VGPR is safe: MFMA captures operands at issue;
// a ds_read placed after the consuming mmac may overwrite those regs --
// the pattern R16's p3-shadow already validated):
//   p0: stage Ah1(t+1,IDLE) |BAR| ldB b1(t); mmac00               |BAR|
//   p1: stage Bh0(t+2)      |BAR| mmac01; ldAm mh1(t) m0..m3      |BAR|
//   p2: stage Bh1(t+2)      |BAR| mmac11; VM4(/VM0)               |BAR|
//   p3: stage Ah0(t+2)      |BAR| mmac10; ldB b0(t+1); ldAm mh0(t+1) m0..m3 |BAR|
// Every operand now lands >=1 interval before its consumer -> no lgkm stall
// inside any mmac cluster.
//
// Ledger (re-audited; per-wave regions: wave wr reads A region h=wr only,
// wave reads B region nh as staged):
//  RAW: p3 reads of t+1: VM4@p2 FIFO keeps 4 newest (Bh0/Bh1(t+2)), drains
//   ALL of t+1 (Ah1(t+1)@p0(t), trio@p1/p2/p3(t-1)); +BAR(p2) => sound.
//   b1(t)@p0: staged p2(t-2), drained VM4@p2(t-1)+BAR.  a_mh1(t)@p1: region
//   Ah0(t)@p3(t-2) [wr=0] / Ah1(t)@p0(t-1) [wr=1], both drained VM4@p2(t-1).
//  WAR: Bh0(t+2)@p1 vs b0(t) read@p3(t-1) (lgkm < mmac00@p0 < BAR(p0)) OK.
//   Bh1(t+2)@p2 vs b1(t) read@p0 (lgkm < mmac01@p1 < BAR(p1)) OK.
//   Ah0(t+2)@p3 vs wr=0 reads: a_mh1(t)@p1 (lgkm < mmac11@p2 < BAR(p2)) OK.
//   Ah1(t+1)@p0 -> IDLE buf; last reads of that region are tile t-1's,
//   complete < BAR(p1,t-1) / BAR(p0,t-1) OK.
//  Tails: VM0@p2 when tt+2>=NT; stages/preloads guarded.
// ---------------------------------------------------------------------------
__global__ __launch_bounds__(512, 2) void qgemm_kernel(const bf16_t* __restrict__ A,
                                                       const bf16_t* __restrict__ Bt,
                                                       const float* __restrict__ bias,
                                                       float* __restrict__ C) {
    constexpr int N = 4096, K = 4096;
    constexpr int NT = K / 64;
    extern __shared__ __align__(16) char lds[];

    const int tid = threadIdx.x;
    const int w = tid >> 6;
    const int lane = tid & 63;
    const int l15 = lane & 15, l4 = lane >> 4;
    const int wr = w >> 2, wc = w & 3;  // 2 x 4 wave grid

    // XCD-aware swizzle (512 = 8*64, bijective)
    const int wg = blockIdx.x;
    const int swz = (wg & 7) * 64 + (wg >> 3);
    const int brow = (swz >> 4) * 256;  // 32 tile rows
    const int bcol = (swz & 15) * 256;  // 16 tile cols

    // staging: LDS stores k-block' = kb ^ (row&7); dest linear, global source
    // k-block for lane slot (lane&7) at row (lane>>3) is the inverse perm:
    const int srow = lane >> 3;
    const int skb = (lane & 7) ^ (lane >> 3);

    auto stageA = [&](int buf, int h, int tt) {
#pragma unroll
        for (int q = 0; q < 2; ++q) {
            const bf16_t* src = A + (size_t)(brow + h * 128 + w * 16 + q * 8 + srow) * K +
                                tt * 64 + skb * 8;
            GLD16(src, lds + buf * 32768 + h * 16384 + w * 2048 + q * 1024);
        }
    };
    auto stageB = [&](int buf, int h, int tt) {
#pragma unroll
        for (int q = 0; q < 2; ++q) {
            const bf16_t* src = Bt + (size_t)(bcol + h * 128 + w * 16 + q * 8 + srow) * K +
                                tt * 64 + skb * 8;
            GLD16(src, lds + 65536 + buf * 32768 + h * 16384 + w * 2048 + q * 1024);
        }
    };

    f32x4 acc[8][4] = {};
    bf16x8 a[4][2], b0[2][2], b1[2][2];

    // one A m-frag (2 reads): row = wr-half, mh sub-half, frag m
    auto ldAm = [&](int buf, int mh, int m) {
#pragma unroll
        for (int c = 0; c < 2; ++c)
            a[m][c] = *(const bf16x8*)(lds + buf * 32768 + wr * 16384 +
                                       (mh * 64 + m * 16 + l15) * 128 +
                                       ((c * 4 + l4) ^ (l15 & 7)) * 16);
    };
    // B frags: nh selects the STAGING half; wave cols = nh*128 + wc*32 + n*16
    auto ldB = [&](int buf, int nh, bf16x8(&b)[2][2]) {
#pragma unroll
        for (int n = 0; n < 2; ++n)
#pragma unroll
            for (int c = 0; c < 2; ++c)
                b[n][c] = *(const bf16x8*)(lds + 65536 + buf * 32768 + nh * 16384 +
                                           (wc * 32 + n * 16 + l15) * 128 +
                                           ((c * 4 + l4) ^ (l15 & 7)) * 16);
    };
    // c outermost (R15): 8 independent MFMAs between accumulator reuses.
    auto mmac = [&](int mh, int nh, bf16x8(&b)[2][2]) {
        __builtin_amdgcn_s_setprio(1);
#pragma unroll
        for (int c = 0; c < 2; ++c)
#pragma unroll
            for (int m = 0; m < 4; ++m)
#pragma unroll
                for (int n = 0; n < 2; ++n)
                    acc[mh * 4 + m][nh * 2 + n] = __builtin_amdgcn_mfma_f32_16x16x32_bf16(
                        a[m][c], b[n][c], acc[mh * 4 + m][nh * 2 + n], 0, 0, 0);
        __builtin_amdgcn_s_setprio(0);
    };

// R16 tile body with decoupled reads; LITERAL buffer index CUR.
#define TILE_BODY(CUR, TT)                                                    \
    {                                                                         \
        const int tt = (TT);                                                  \
        /* p0: consume a(mh0),b0 (read @p3 prev); read b1(t); stage Ah1 */    \
        if (tt + 1 < NT) stageA((CUR) ^ 1, 1, tt + 1);                        \
        BAR();                                                                \
        ldB((CUR), 1, b1);                                                    \
        mmac(0, 0, b0);                                                       \
        BAR();                                                                \
        /* p1: consume a(mh0),b1; then read a(mh1) m0..m3; stage Bh0 */       \
        if (tt + 2 < NT) stageB((CUR), 0, tt + 2);                            \
        BAR();                                                                \
        mmac(0, 1, b1);                                                       \
        ldAm((CUR), 1, 0);                                                    \
        ldAm((CUR), 1, 1);                                                    \
        ldAm((CUR), 1, 2);                                                    \
        ldAm((CUR), 1, 3);                                                    \
        BAR();                                                                \
        /* p2: consume a(mh1),b1 (read @p1); stage Bh1; counted drain */      \
        if (tt + 2 < NT) stageB((CUR), 1, tt + 2);                            \
        BAR();                                                                \
        mmac(1, 1, b1);                                                       \
        if (tt + 2 < NT) {                                                    \
            WAIT_VM4();                                                       \
        } else {                                                              \
            WAIT_VM0();                                                       \
        }                                                                     \
        BAR();                                                                \
        /* p3: consume a(mh1),b0; stage Ah0; preload b0 + FULL a(mh0) t+1 */  \
        if (tt + 2 < NT) stageA((CUR), 0, tt + 2);                            \
        BAR();                                                                \
        mmac(1, 0, b0);                                                       \
        if (tt + 1 < NT) {                                                    \
            ldB((CUR) ^ 1, 0, b0);                                            \
            ldAm((CUR) ^ 1, 0, 0);                                            \
            ldAm((CUR) ^ 1, 0, 1);                                            \
            ldAm((CUR) ^ 1, 0, 2);                                            \
            ldAm((CUR) ^ 1, 0, 3);                                            \
        }                                                                     \
        BAR();                                                                \
    }

    // prologue: tile0 full (8 loads, buf0) + tile1's Bh0/Bh1/Ah0 (6, buf1);
    // VM6 drains tile0 (issuer drain), BAR (common), preload b0 + full a_mh0.
    stageA(0, 0, 0);
    stageA(0, 1, 0);
    stageB(0, 0, 0);
    stageB(0, 1, 0);
    stageB(1, 0, 1);
    stageB(1, 1, 1);
    stageA(1, 0, 1);
    WAIT_VM6();
    BAR();
    ldB(0, 0, b0);
    ldAm(0, 0, 0);
    ldAm(0, 0, 1);
    ldAm(0, 0, 2);
    ldAm(0, 0, 3);

    // main loop: 2 K-tiles per iteration, buf indices compile-time 0/1
    for (int it = 0; it < NT / 2; ++it) {
        TILE_BODY(0, 2 * it);
        TILE_BODY(1, 2 * it + 1);
    }
#undef TILE_BODY

    // epilogue: C/D layout col = lane&15, row = (lane>>4)*4 + i.
    // B mapping: global n -> col = (n>>1)*128 + wc*32 + (n&1)*16
#pragma unroll
    for (int n = 0; n < 4; ++n) {
        const int col = bcol + (n >> 1) * 128 + wc * 32 + (n & 1) * 16 + l15;
        const float bv = bias[col];
#pragma unroll
        for (int m = 0; m < 8; ++m) {
            const int row0 = brow + wr * 128 + m * 16 + l4 * 4;
            const f32x4 v = acc[m][n];
#pragma unroll
            for (int i = 0; i < 4; ++i)
                C[(size_t)(row0 + i) * N + col] = v[i] + bv;
        }
    }
}

// ---------------------------------------------------------------------------
extern "C" void kernel_launch(void* const* d_in, const int* in_sizes, int n_in,
                              void* d_out, int out_size, void* d_ws, size_t ws_size,
                              hipStream_t stream) {
    const float* x = (const float*)d_in[0];
    const float* Wa = (const float*)d_in[1];
    const float* Wb = (const float*)d_in[2];
    const float* Wc = (const float*)d_in[3];
    const float* Wd = (const float*)d_in[4];
    const float* bias = (const float*)d_in[5];
    float* out = (float*)d_out;

    const int M = 8192, N = 4096, K = 4096;

    bf16_t* xb = (bf16_t*)d_ws;       // [M][K] bf16
    bf16_t* Mt = xb + (size_t)M * K;  // [N][K] bf16

    cvt_x_kernel<<<4096, 256, 0, stream>>>(x, xb, (M * K) / 4);
    pack_w_kernel<<<dim3(64, 64), 256, 0, stream>>>(Wa, Wb, Wc, Wd, Mt);

    (void)hipFuncSetAttribute((const void*)qgemm_kernel,
                              hipFuncAttributeMaxDynamicSharedMemorySize, 131072);
    qgemm_kernel<<<dim3((M / 256) * (N / 256)), 512, 131072, stream>>>(xb, Mt, bias, out);
}

// Round 19
// 276.040 us; speedup vs baseline: 1.6350x; 1.0203x over previous
//
#include <hip/hip_runtime.h>
#include <hip/hip_bf16.h>
#include <cstdint>
#include <cstddef>

typedef __bf16 bf16_t;
typedef __bf16 bf16x4 __attribute__((ext_vector_type(4)));
typedef __bf16 bf16x8 __attribute__((ext_vector_type(8)));
typedef float f32x4 __attribute__((ext_vector_type(4)));

#define GLD16(src, dst)                                                       \
    __builtin_amdgcn_global_load_lds(                                         \
        (const __attribute__((address_space(1))) void*)(src),                 \
        (__attribute__((address_space(3))) void*)(dst), 16, 0, 0)

// s_barrier WITH compiler memory fence (R8 lesson).
#define BAR() asm volatile("s_barrier" ::: "memory")
#define WAIT_VM4() asm volatile("s_waitcnt vmcnt(4)" ::: "memory")
#define WAIT_VM6() asm volatile("s_waitcnt vmcnt(6)" ::: "memory")
#define WAIT_VM0() asm volatile("s_waitcnt vmcnt(0)" ::: "memory")

// ---------------------------------------------------------------------------
// x fp32 -> bf16, vectorized (G13)
// ---------------------------------------------------------------------------
__global__ __launch_bounds__(256) void cvt_x_kernel(const float* __restrict__ x,
                                                    bf16_t* __restrict__ xb, int n4) {
    int idx = blockIdx.x * blockDim.x + threadIdx.x;
    int stride = gridDim.x * blockDim.x;
    const f32x4* xv = (const f32x4*)x;
    bf16x4* ov = (bf16x4*)xb;
    for (int i = idx; i < n4; i += stride) {
        f32x4 v = xv[i];
        bf16x4 o;
        o[0] = (bf16_t)v[0];
        o[1] = (bf16_t)v[1];
        o[2] = (bf16_t)v[2];
        o[3] = (bf16_t)v[3];
        ov[i] = o;
    }
}

// ---------------------------------------------------------------------------
// Build Mt[n][k] (bf16, [N][K]) from the quaternion Hamilton block structure.
// ---------------------------------------------------------------------------
__global__ __launch_bounds__(256) void pack_w_kernel(const float* __restrict__ Wa,
                                                     const float* __restrict__ Wb,
                                                     const float* __restrict__ Wc,
                                                     const float* __restrict__ Wd,
                                                     bf16_t* __restrict__ Mt) {
    __shared__ float tile[64][65];
    const int kb = blockIdx.x * 64;
    const int nb = blockIdx.y * 64;
    const int i = kb >> 10;
    const int j = nb >> 10;

    const float* W[4] = {Wa, Wb, Wc, Wd};
    const int srcIdx[4][4] = {{0, 1, 2, 3}, {1, 0, 3, 2}, {2, 3, 0, 1}, {3, 2, 1, 0}};
    const float sgn[4][4] = {{1.f, 1.f, 1.f, 1.f},
                             {-1.f, 1.f, -1.f, 1.f},
                             {-1.f, 1.f, 1.f, -1.f},
                             {-1.f, -1.f, 1.f, 1.f}};
    const float* Ws = W[srcIdx[i][j]];
    const float s = sgn[i][j];

    const int kq = kb & 1023;
    const int nq = nb & 1023;
    const int tx = threadIdx.x & 63;
    const int ty = threadIdx.x >> 6;

    for (int r = ty; r < 64; r += 4)
        tile[r][tx] = Ws[(size_t)(kq + r) * 1024 + (nq + tx)];
    __syncthreads();
    for (int r = ty; r < 64; r += 4)
        Mt[(size_t)(nb + r) * 4096 + (kb + tx)] = (bf16_t)(s * tile[tx][r]);
}

// ---------------------------------------------------------------------------
// 256x256 GEMM — R18 schedule with ONE barrier per phase (4/tile, was 8).
//
// Pipe arithmetic (R18 post-mortem): MFMA = 2483 cy/SIMD/tile, LDS-read =
// 2304 cy/CU/tile; measured 4464 ~= SUM (no overlap); m201 proves 3300 on
// identical geometry.  Reads are already decoupled >=1 phase from consumers
// (R18), so lgkm stalls are not the cause.  Remaining structural overhead:
// 8 block-wide barrier convergences per tile.  This round deletes the 4
// mid-phase barriers, merging [stage][compute] into one region per phase:
//   p0: stageAh1(t+1,IDLE); ldB b1(t); mmac00                          |BAR|
//   p1: stageBh0(t+2);      mmac01; ldAm mh1(t) m0..m3                 |BAR|
//   p2: stageBh1(t+2);      mmac11; VM4(/VM0)                          |BAR|
//   p3: stageAh0(t+2);      mmac10; preload b0,a_mh0(t+1)              |BAR|
//
// Re-audited 1-barrier ledger:
//  WAR (stage vs other waves' reads of same region): Bh0(t+2)@p1 vs b0(t)
//   [read @p3(t-1), lgkm < mmac00@p0 < BAR(p0)] OK; Bh1(t+2)@p2 vs b1(t)
//   [lgkm < mmac01@p1 < BAR(p1)] OK; Ah0(t+2)@p3 vs a-reads [a_mh1 lgkm <
//   mmac11@p2 < BAR(p2)] OK; Ah1(t+1)@p0 -> IDLE buf [that region's last
//   reads completed in tile t-1] OK.  All have >=1 common barrier between
//   read-completion point and stage issue.
//  RAW (reads of staged data): VM4@p2 FIFO (12 outstanding: 4 kept from
//   p2(t-1) + Ah0(t+1)@p3(t-1) + Ah1(t+1)@p0 + Bh0/Bh1(t+2)@p1/p2) keeps 4
//   newest = Bh0/Bh1(t+2), drains ALL of t+1; BAR(p2) makes it common ->
//   p3 preloads sound.  b1(t)@p0 / a_mh1(t)@p1: staged >=2 tiles back,
//   drained by VM4@p2(t-1) + BAR.  Stage-vs-VM4 program order preserved
//   (GLD16 side effect cannot cross asm memory clobber).
//  Tails: VM0@p2 when tt+2>=NT (drains the 8 outstanding t+1 loads before
//   p3 preloads); stages/preloads guarded as in R18.
// ---------------------------------------------------------------------------
__global__ __launch_bounds__(512, 2) void qgemm_kernel(const bf16_t* __restrict__ A,
                                                       const bf16_t* __restrict__ Bt,
                                                       const float* __restrict__ bias,
                                                       float* __restrict__ C) {
    constexpr int N = 4096, K = 4096;
    constexpr int NT = K / 64;
    extern __shared__ __align__(16) char lds[];

    const int tid = threadIdx.x;
    const int w = tid >> 6;
    const int lane = tid & 63;
    const int l15 = lane & 15, l4 = lane >> 4;
    const int wr = w >> 2, wc = w & 3;  // 2 x 4 wave grid

    // XCD-aware swizzle (512 = 8*64, bijective)
    const int wg = blockIdx.x;
    const int swz = (wg & 7) * 64 + (wg >> 3);
    const int brow = (swz >> 4) * 256;  // 32 tile rows
    const int bcol = (swz & 15) * 256;  // 16 tile cols

    // staging: LDS stores k-block' = kb ^ (row&7); dest linear, global source
    // k-block for lane slot (lane&7) at row (lane>>3) is the inverse perm:
    const int srow = lane >> 3;
    const int skb = (lane & 7) ^ (lane >> 3);

    auto stageA = [&](int buf, int h, int tt) {
#pragma unroll
        for (int q = 0; q < 2; ++q) {
            const bf16_t* src = A + (size_t)(brow + h * 128 + w * 16 + q * 8 + srow) * K +
                                tt * 64 + skb * 8;
            GLD16(src, lds + buf * 32768 + h * 16384 + w * 2048 + q * 1024);
        }
    };
    auto stageB = [&](int buf, int h, int tt) {
#pragma unroll
        for (int q = 0; q < 2; ++q) {
            const bf16_t* src = Bt + (size_t)(bcol + h * 128 + w * 16 + q * 8 + srow) * K +
                                tt * 64 + skb * 8;
            GLD16(src, lds + 65536 + buf * 32768 + h * 16384 + w * 2048 + q * 1024);
        }
    };

    f32x4 acc[8][4] = {};
    bf16x8 a[4][2], b0[2][2], b1[2][2];

    // one A m-frag (2 reads): row = wr-half, mh sub-half, frag m
    auto ldAm = [&](int buf, int mh, int m) {
#pragma unroll
        for (int c = 0; c < 2; ++c)
            a[m][c] = *(const bf16x8*)(lds + buf * 32768 + wr * 16384 +
                                       (mh * 64 + m * 16 + l15) * 128 +
                                       ((c * 4 + l4) ^ (l15 & 7)) * 16);
    };
    // B frags: nh selects the STAGING half; wave cols = nh*128 + wc*32 + n*16
    auto ldB = [&](int buf, int nh, bf16x8(&b)[2][2]) {
#pragma unroll
        for (int n = 0; n < 2; ++n)
#pragma unroll
            for (int c = 0; c < 2; ++c)
                b[n][c] = *(const bf16x8*)(lds + 65536 + buf * 32768 + nh * 16384 +
                                           (wc * 32 + n * 16 + l15) * 128 +
                                           ((c * 4 + l4) ^ (l15 & 7)) * 16);
    };
    // c outermost (R15): 8 independent MFMAs between accumulator reuses.
    auto mmac = [&](int mh, int nh, bf16x8(&b)[2][2]) {
        __builtin_amdgcn_s_setprio(1);
#pragma unroll
        for (int c = 0; c < 2; ++c)
#pragma unroll
            for (int m = 0; m < 4; ++m)
#pragma unroll
                for (int n = 0; n < 2; ++n)
                    acc[mh * 4 + m][nh * 2 + n] = __builtin_amdgcn_mfma_f32_16x16x32_bf16(
                        a[m][c], b[n][c], acc[mh * 4 + m][nh * 2 + n], 0, 0, 0);
        __builtin_amdgcn_s_setprio(0);
    };

// One K-tile, LITERAL buffer index CUR, ONE barrier per phase.
#define TILE_BODY(CUR, TT)                                                    \
    {                                                                         \
        const int tt = (TT);                                                  \
        /* p0: consume a(mh0),b0 (preloaded @p3 prev); read b1(t) */          \
        if (tt + 1 < NT) stageA((CUR) ^ 1, 1, tt + 1);                        \
        ldB((CUR), 1, b1);                                                    \
        mmac(0, 0, b0);                                                       \
        BAR();                                                                \
        /* p1: consume a(mh0),b1; then read a(mh1) m0..m3 */                  \
        if (tt + 2 < NT) stageB((CUR), 0, tt + 2);                            \
        mmac(0, 1, b1);                                                       \
        ldAm((CUR), 1, 0);                                                    \
        ldAm((CUR), 1, 1);                                                    \
        ldAm((CUR), 1, 2);                                                    \
        ldAm((CUR), 1, 3);                                                    \
        BAR();                                                                \
        /* p2: consume a(mh1),b1; counted drain BEFORE the barrier */         \
        if (tt + 2 < NT) stageB((CUR), 1, tt + 2);                            \
        mmac(1, 1, b1);                                                       \
        if (tt + 2 < NT) {                                                    \
            WAIT_VM4();                                                       \
        } else {                                                              \
            WAIT_VM0();                                                       \
        }                                                                     \
        BAR();                                                                \
        /* p3: consume a(mh1),b0; preload b0 + full a(mh0) of t+1 */          \
        if (tt + 2 < NT) stageA((CUR), 0, tt + 2);                            \
        mmac(1, 0, b0);                                                       \
        if (tt + 1 < NT) {                                                    \
            ldB((CUR) ^ 1, 0, b0);                                            \
            ldAm((CUR) ^ 1, 0, 0);                                            \
            ldAm((CUR) ^ 1, 0, 1);                                            \
            ldAm((CUR) ^ 1, 0, 2);                                            \
            ldAm((CUR) ^ 1, 0, 3);                                            \
        }                                                                     \
        BAR();                                                                \
    }

    // prologue: tile0 full (8 loads, buf0) + tile1's Bh0/Bh1/Ah0 (6, buf1);
    // VM6 drains tile0 (issuer drain), BAR (common), preload b0 + full a_mh0.
    stageA(0, 0, 0);
    stageA(0, 1, 0);
    stageB(0, 0, 0);
    stageB(0, 1, 0);
    stageB(1, 0, 1);
    stageB(1, 1, 1);
    stageA(1, 0, 1);
    WAIT_VM6();
    BAR();
    ldB(0, 0, b0);
    ldAm(0, 0, 0);
    ldAm(0, 0, 1);
    ldAm(0, 0, 2);
    ldAm(0, 0, 3);

    // main loop: 2 K-tiles per iteration, buf indices compile-time 0/1
    for (int it = 0; it < NT / 2; ++it) {
        TILE_BODY(0, 2 * it);
        TILE_BODY(1, 2 * it + 1);
    }
#undef TILE_BODY

    // epilogue: C/D layout col = lane&15, row = (lane>>4)*4 + i.
    // B mapping: global n -> col = (n>>1)*128 + wc*32 + (n&1)*16
#pragma unroll
    for (int n = 0; n < 4; ++n) {
        const int col = bcol + (n >> 1) * 128 + wc * 32 + (n & 1) * 16 + l15;
        const float bv = bias[col];
#pragma unroll
        for (int m = 0; m < 8; ++m) {
            const int row0 = brow + wr * 128 + m * 16 + l4 * 4;
            const f32x4 v = acc[m][n];
#pragma unroll
            for (int i = 0; i < 4; ++i)
                C[(size_t)(row0 + i) * N + col] = v[i] + bv;
        }
    }
}

// ---------------------------------------------------------------------------
extern "C" void kernel_launch(void* const* d_in, const int* in_sizes, int n_in,
                              void* d_out, int out_size, void* d_ws, size_t ws_size,
                              hipStream_t stream) {
    const float* x = (const float*)d_in[0];
    const float* Wa = (const float*)d_in[1];
    const float* Wb = (const float*)d_in[2];
    const float* Wc = (const float*)d_in[3];
    const float* Wd = (const float*)d_in[4];
    const float* bias = (const float*)d_in[5];
    float* out = (float*)d_out;

    const int M = 8192, N = 4096, K = 4096;

    bf16_t* xb = (bf16_t*)d_ws;       // [M][K] bf16
    bf16_t* Mt = xb + (size_t)M * K;  // [N][K] bf16

    cvt_x_kernel<<<4096, 256, 0, stream>>>(x, xb, (M * K) / 4);
    pack_w_kernel<<<dim3(64, 64), 256, 0, stream>>>(Wa, Wb, Wc, Wd, Mt);

    (void)hipFuncSetAttribute((const void*)qgemm_kernel,
                              hipFuncAttributeMaxDynamicSharedMemorySize, 131072);
    qgemm_kernel<<<dim3((M / 256) * (N / 256)), 512, 131072, stream>>>(xb, Mt, bias, out);
}

// Round 20
// 275.639 us; speedup vs baseline: 1.6374x; 1.0015x over previous
//
#include <hip/hip_runtime.h>
#include <hip/hip_bf16.h>
#include <cstdint>
#include <cstddef>

typedef __bf16 bf16_t;
typedef __bf16 bf16x4 __attribute__((ext_vector_type(4)));
typedef __bf16 bf16x8 __attribute__((ext_vector_type(8)));
typedef float f32x4 __attribute__((ext_vector_type(4)));

#define GLD16(src, dst)                                                       \
    __builtin_amdgcn_global_load_lds(                                         \
        (const __attribute__((address_space(1))) void*)(src),                 \
        (__attribute__((address_space(3))) void*)(dst), 16, 0, 0)

// s_barrier WITH compiler memory fence (R8 lesson).
#define BAR() asm volatile("s_barrier" ::: "memory")
#define WAIT_VM4() asm volatile("s_waitcnt vmcnt(4)" ::: "memory")
#define WAIT_VM6() asm volatile("s_waitcnt vmcnt(6)" ::: "memory")
#define WAIT_VM0() asm volatile("s_waitcnt vmcnt(0)" ::: "memory")

// ---------------------------------------------------------------------------
// x fp32 -> bf16, vectorized (G13)
// ---------------------------------------------------------------------------
__global__ __launch_bounds__(256) void cvt_x_kernel(const float* __restrict__ x,
                                                    bf16_t* __restrict__ xb, int n4) {
    int idx = blockIdx.x * blockDim.x + threadIdx.x;
    int stride = gridDim.x * blockDim.x;
    const f32x4* xv = (const f32x4*)x;
    bf16x4* ov = (bf16x4*)xb;
    for (int i = idx; i < n4; i += stride) {
        f32x4 v = xv[i];
        bf16x4 o;
        o[0] = (bf16_t)v[0];
        o[1] = (bf16_t)v[1];
        o[2] = (bf16_t)v[2];
        o[3] = (bf16_t)v[3];
        ov[i] = o;
    }
}

// ---------------------------------------------------------------------------
// Build Mt[n][k] (bf16, [N][K]) from the quaternion Hamilton block structure.
// ---------------------------------------------------------------------------
__global__ __launch_bounds__(256) void pack_w_kernel(const float* __restrict__ Wa,
                                                     const float* __restrict__ Wb,
                                                     const float* __restrict__ Wc,
                                                     const float* __restrict__ Wd,
                                                     bf16_t* __restrict__ Mt) {
    __shared__ float tile[64][65];
    const int kb = blockIdx.x * 64;
    const int nb = blockIdx.y * 64;
    const int i = kb >> 10;
    const int j = nb >> 10;

    const float* W[4] = {Wa, Wb, Wc, Wd};
    const int srcIdx[4][4] = {{0, 1, 2, 3}, {1, 0, 3, 2}, {2, 3, 0, 1}, {3, 2, 1, 0}};
    const float sgn[4][4] = {{1.f, 1.f, 1.f, 1.f},
                             {-1.f, 1.f, -1.f, 1.f},
                             {-1.f, 1.f, 1.f, -1.f},
                             {-1.f, -1.f, 1.f, 1.f}};
    const float* Ws = W[srcIdx[i][j]];
    const float s = sgn[i][j];

    const int kq = kb & 1023;
    const int nq = nb & 1023;
    const int tx = threadIdx.x & 63;
    const int ty = threadIdx.x >> 6;

    for (int r = ty; r < 64; r += 4)
        tile[r][tx] = Ws[(size_t)(kq + r) * 1024 + (nq + tx)];
    __syncthreads();
    for (int r = ty; r < 64; r += 4)
        Mt[(size_t)(nb + r) * 4096 + (kb + tx)] = (bf16_t)(s * tile[tx][r]);
}

// ---------------------------------------------------------------------------
// 256x256 GEMM — R19 protocol (4 barriers/tile, unrolled x2) + READ/MFMA
// ISSUE INTERLEAVE in p1/p3.
//
// R19 model: regions emit [16-MFMA burst][read burst]; in-order wave issue
// means the LDS pipe idles during the MFMA burst and vice versa, and 2
// lockstepped waves/SIMD align their bursts -> pipes serialize (~35% overlap,
// tile 4258 cy vs MFMA 2483 + LDS ~2550).  This round splits p1/p3's MFMA
// cluster into two 8-MFMA pairs and places each a[m]-pair RELOAD immediately
// after its last consuming MFMA (reg-WAR after issue is safe -- the R18
// shadow pattern): the read issues sit inside the MFMA stream, so the LDS
// pipe is fed while the MFMA pipe drains.  Dependency distance within a pair
// = 4 independent MFMAs (c-outer over 2m x 2n).
// Protocol/ledger byte-identical to passing R19:
//   p0: stageAh1(t+1,IDLE); ldB b1(t); mmac00                          |BAR|
//   p1: stageBh0(t+2); [8xMFMA m01|ldAm mh1 m0,m1|8xMFMA m23|ldAm m2,m3]|BAR|
//   p2: stageBh1(t+2); mmac11; VM4(/VM0)                               |BAR|
//   p3: stageAh0(t+2); [8xMFMA m01|pre a m0,m1|8xMFMA m23|pre a m2,m3, b0]|BAR|
// (WAR/RAW edges unchanged: read phases, stage phases, VM4@p2, tails.)
// ---------------------------------------------------------------------------
__global__ __launch_bounds__(512, 2) void qgemm_kernel(const bf16_t* __restrict__ A,
                                                       const bf16_t* __restrict__ Bt,
                                                       const float* __restrict__ bias,
                                                       float* __restrict__ C) {
    constexpr int N = 4096, K = 4096;
    constexpr int NT = K / 64;
    extern __shared__ __align__(16) char lds[];

    const int tid = threadIdx.x;
    const int w = tid >> 6;
    const int lane = tid & 63;
    const int l15 = lane & 15, l4 = lane >> 4;
    const int wr = w >> 2, wc = w & 3;  // 2 x 4 wave grid

    // XCD-aware swizzle (512 = 8*64, bijective)
    const int wg = blockIdx.x;
    const int swz = (wg & 7) * 64 + (wg >> 3);
    const int brow = (swz >> 4) * 256;  // 32 tile rows
    const int bcol = (swz & 15) * 256;  // 16 tile cols

    // staging: LDS stores k-block' = kb ^ (row&7); dest linear, global source
    // k-block for lane slot (lane&7) at row (lane>>3) is the inverse perm:
    const int srow = lane >> 3;
    const int skb = (lane & 7) ^ (lane >> 3);

    auto stageA = [&](int buf, int h, int tt) {
#pragma unroll
        for (int q = 0; q < 2; ++q) {
            const bf16_t* src = A + (size_t)(brow + h * 128 + w * 16 + q * 8 + srow) * K +
                                tt * 64 + skb * 8;
            GLD16(src, lds + buf * 32768 + h * 16384 + w * 2048 + q * 1024);
        }
    };
    auto stageB = [&](int buf, int h, int tt) {
#pragma unroll
        for (int q = 0; q < 2; ++q) {
            const bf16_t* src = Bt + (size_t)(bcol + h * 128 + w * 16 + q * 8 + srow) * K +
                                tt * 64 + skb * 8;
            GLD16(src, lds + 65536 + buf * 32768 + h * 16384 + w * 2048 + q * 1024);
        }
    };

    f32x4 acc[8][4] = {};
    bf16x8 a[4][2], b0[2][2], b1[2][2];

    // one A m-frag (2 reads): row = wr-half, mh sub-half, frag m
    auto ldAm = [&](int buf, int mh, int m) {
#pragma unroll
        for (int c = 0; c < 2; ++c)
            a[m][c] = *(const bf16x8*)(lds + buf * 32768 + wr * 16384 +
                                       (mh * 64 + m * 16 + l15) * 128 +
                                       ((c * 4 + l4) ^ (l15 & 7)) * 16);
    };
    // B frags: nh selects the STAGING half; wave cols = nh*128 + wc*32 + n*16
    auto ldB = [&](int buf, int nh, bf16x8(&b)[2][2]) {
#pragma unroll
        for (int n = 0; n < 2; ++n)
#pragma unroll
            for (int c = 0; c < 2; ++c)
                b[n][c] = *(const bf16x8*)(lds + 65536 + buf * 32768 + nh * 16384 +
                                           (wc * 32 + n * 16 + l15) * 128 +
                                           ((c * 4 + l4) ^ (l15 & 7)) * 16);
    };
    // full 16-MFMA cluster (c outermost: 8 independent between acc reuses)
    auto mmac = [&](int mh, int nh, bf16x8(&b)[2][2]) {
        __builtin_amdgcn_s_setprio(1);
#pragma unroll
        for (int c = 0; c < 2; ++c)
#pragma unroll
            for (int m = 0; m < 4; ++m)
#pragma unroll
                for (int n = 0; n < 2; ++n)
                    acc[mh * 4 + m][nh * 2 + n] = __builtin_amdgcn_mfma_f32_16x16x32_bf16(
                        a[m][c], b[n][c], acc[mh * 4 + m][nh * 2 + n], 0, 0, 0);
        __builtin_amdgcn_s_setprio(0);
    };
    // 8-MFMA pair cluster: m in {2*mp, 2*mp+1}; c outer -> dep distance 4
    auto mmac_pair = [&](int mh, int nh, int mp, bf16x8(&b)[2][2]) {
        __builtin_amdgcn_s_setprio(1);
#pragma unroll
        for (int c = 0; c < 2; ++c)
#pragma unroll
            for (int m2 = 0; m2 < 2; ++m2)
#pragma unroll
                for (int n = 0; n < 2; ++n) {
                    const int m = mp * 2 + m2;
                    acc[mh * 4 + m][nh * 2 + n] = __builtin_amdgcn_mfma_f32_16x16x32_bf16(
                        a[m][c], b[n][c], acc[mh * 4 + m][nh * 2 + n], 0, 0, 0);
                }
        __builtin_amdgcn_s_setprio(0);
    };

// One K-tile, LITERAL buffer index CUR, ONE barrier per phase, p1/p3
// read-issues chained into the MFMA stream via reg-WAR.
#define TILE_BODY(CUR, TT)                                                    \
    {                                                                         \
        const int tt = (TT);                                                  \
        /* p0: consume a(mh0),b0; read b1(t) ahead of mmac00 */               \
        if (tt + 1 < NT) stageA((CUR) ^ 1, 1, tt + 1);                        \
        ldB((CUR), 1, b1);                                                    \
        mmac(0, 0, b0);                                                       \
        BAR();                                                                \
        /* p1: consume a(mh0),b1; reload a with mh1 interleaved per-pair */   \
        if (tt + 2 < NT) stageB((CUR), 0, tt + 2);                            \
        mmac_pair(0, 1, 0, b1);                                               \
        ldAm((CUR), 1, 0);                                                    \
        ldAm((CUR), 1, 1);                                                    \
        mmac_pair(0, 1, 1, b1);                                               \
        ldAm((CUR), 1, 2);                                                    \
        ldAm((CUR), 1, 3);                                                    \
        BAR();                                                                \
        /* p2: consume a(mh1),b1; counted drain BEFORE the barrier */         \
        if (tt + 2 < NT) stageB((CUR), 1, tt + 2);                            \
        mmac(1, 1, b1);                                                       \
        if (tt + 2 < NT) {                                                    \
            WAIT_VM4();                                                       \
        } else {                                                              \
            WAIT_VM0();                                                       \
        }                                                                     \
        BAR();                                                                \
        /* p3: consume a(mh1),b0; preload t+1 interleaved per-pair */         \
        if (tt + 2 < NT) stageA((CUR), 0, tt + 2);                            \
        mmac_pair(1, 0, 0, b0);                                               \
        if (tt + 1 < NT) {                                                    \
            ldAm((CUR) ^ 1, 0, 0);                                            \
            ldAm((CUR) ^ 1, 0, 1);                                            \
        }                                                                     \
        mmac_pair(1, 0, 1, b0);                                               \
        if (tt + 1 < NT) {                                                    \
            ldAm((CUR) ^ 1, 0, 2);                                            \
            ldAm((CUR) ^ 1, 0, 3);                                            \
            ldB((CUR) ^ 1, 0, b0);                                            \
        }                                                                     \
        BAR();                                                                \
    }

    // prologue: tile0 full (8 loads, buf0) + tile1's Bh0/Bh1/Ah0 (6, buf1);
    // VM6 drains tile0 (issuer drain), BAR (common), preload b0 + full a_mh0.
    stageA(0, 0, 0);
    stageA(0, 1, 0);
    stageB(0, 0, 0);
    stageB(0, 1, 0);
    stageB(1, 0, 1);
    stageB(1, 1, 1);
    stageA(1, 0, 1);
    WAIT_VM6();
    BAR();
    ldB(0, 0, b0);
    ldAm(0, 0, 0);
    ldAm(0, 0, 1);
    ldAm(0, 0, 2);
    ldAm(0, 0, 3);

    // main loop: 2 K-tiles per iteration, buf indices compile-time 0/1
    for (int it = 0; it < NT / 2; ++it) {
        TILE_BODY(0, 2 * it);
        TILE_BODY(1, 2 * it + 1);
    }
#undef TILE_BODY

    // epilogue: C/D layout col = lane&15, row = (lane>>4)*4 + i.
    // B mapping: global n -> col = (n>>1)*128 + wc*32 + (n&1)*16
#pragma unroll
    for (int n = 0; n < 4; ++n) {
        const int col = bcol + (n >> 1) * 128 + wc * 32 + (n & 1) * 16 + l15;
        const float bv = bias[col];
#pragma unroll
        for (int m = 0; m < 8; ++m) {
            const int row0 = brow + wr * 128 + m * 16 + l4 * 4;
            const f32x4 v = acc[m][n];
#pragma unroll
            for (int i = 0; i < 4; ++i)
                C[(size_t)(row0 + i) * N + col] = v[i] + bv;
        }
    }
}

// ---------------------------------------------------------------------------
extern "C" void kernel_launch(void* const* d_in, const int* in_sizes, int n_in,
                              void* d_out, int out_size, void* d_ws, size_t ws_size,
                              hipStream_t stream) {
    const float* x = (const float*)d_in[0];
    const float* Wa = (const float*)d_in[1];
    const float* Wb = (const float*)d_in[2];
    const float* Wc = (const float*)d_in[3];
    const float* Wd = (const float*)d_in[4];
    const float* bias = (const float*)d_in[5];
    float* out = (float*)d_out;

    const int M = 8192, N = 4096, K = 4096;

    bf16_t* xb = (bf16_t*)d_ws;       // [M][K] bf16
    bf16_t* Mt = xb + (size_t)M * K;  // [N][K] bf16

    cvt_x_kernel<<<4096, 256, 0, stream>>>(x, xb, (M * K) / 4);
    pack_w_kernel<<<dim3(64, 64), 256, 0, stream>>>(Wa, Wb, Wc, Wd, Mt);

    (void)hipFuncSetAttribute((const void*)qgemm_kernel,
                              hipFuncAttributeMaxDynamicSharedMemorySize, 131072);
    qgemm_kernel<<<dim3((M / 256) * (N / 256)), 512, 131072, stream>>>(xb, Mt, bias, out);
}